// Round 1
// baseline (13.178 us; speedup 1.0000x reference)
//
#include <hip/hip_runtime.h>

// NormDistConv: out[n,o,h,w] = max_f |patch(n,:,h,w)[f] - weight[o,f]| + bias[o]
// x: (8,16,32,32) f32, weight: (64,144) f32, bias: (64,) f32, out: (8,64,32,32) f32
//
// Layout: 256 blocks = (32 o-groups x 8 n), 256 threads.
// Each thread: 4 adjacent-w pixels x 2 output channels.
// x staged in padded LDS [8][34][36] (channel-split, 2 phases, <64KB dyn LDS).

#define N_   8
#define C_   16
#define H_   32
#define W_   32
#define O_   64
#define KH_  3
#define KW_  3
#define F_   (C_ * KH_ * KW_)   // 144
#define OG   2                  // output channels per block
#define CPH  8                  // channels per staging phase
#define PADH 34
#define PADW 36                 // row stride (floats): keeps b128 16B-aligned
#define LDS_FLOATS (CPH * PADH * PADW)   // 9792 floats = 39168 B

__global__ __launch_bounds__(256)
void normdist_kernel(const float* __restrict__ x,
                     const float* __restrict__ weight,
                     const float* __restrict__ bias,
                     float* __restrict__ out)
{
    extern __shared__ float xs[];   // [CPH][PADH][PADW]
    const int tid = threadIdx.x;
    const int n   = blockIdx.y;
    const int o0  = blockIdx.x * OG;

    // ---- zero LDS once (borders stay zero across both phases) ----
    {
        float4 z4 = make_float4(0.f, 0.f, 0.f, 0.f);
        float4* xs4 = reinterpret_cast<float4*>(xs);
        #pragma unroll
        for (int i = tid; i < LDS_FLOATS / 4; i += 256)
            xs4[i] = z4;
    }
    __syncthreads();

    // thread -> (h, w0..w0+3)
    const int h  = tid >> 3;          // 0..31
    const int w0 = (tid & 7) << 2;    // 0,4,...,28

    const float* __restrict__ wr = weight + (size_t)o0 * F_;  // block-uniform
    const float* __restrict__ xn = x + (size_t)n * (C_ * H_ * W_);

    float m[OG][4];
    #pragma unroll
    for (int og = 0; og < OG; ++og)
        #pragma unroll
        for (int p = 0; p < 4; ++p)
            m[og][p] = 0.f;   // |x-w| >= 0, so 0 is a safe identity

    #pragma unroll
    for (int cc = 0; cc < C_; cc += CPH) {
        // ---- stage channels [cc, cc+CPH) into LDS interior ----
        {
            const float4* src = reinterpret_cast<const float4*>(xn + cc * (H_ * W_));
            #pragma unroll
            for (int i = tid; i < CPH * H_ * W_ / 4; i += 256) {
                float4 v = src[i];
                int e  = i << 2;
                int c2 = e >> 10;          // /1024
                int hw = e & 1023;
                int hh = hw >> 5;
                int ww = hw & 31;
                float* dst = &xs[c2 * (PADH * PADW) + (hh + 1) * PADW + (ww + 1)];
                dst[0] = v.x; dst[1] = v.y; dst[2] = v.z; dst[3] = v.w;
            }
        }
        __syncthreads();

        // ---- compute over these channels ----
        #pragma unroll
        for (int c2 = 0; c2 < CPH; ++c2) {
            #pragma unroll
            for (int kh = 0; kh < KH_; ++kh) {
                const float* row = &xs[c2 * (PADH * PADW) + (h + kh) * PADW + w0];
                float4 xa = *reinterpret_cast<const float4*>(row);
                float2 xb = *reinterpret_cast<const float2*>(row + 4);
                float xv[6] = {xa.x, xa.y, xa.z, xa.w, xb.x, xb.y};
                const int f = ((cc + c2) * KH_ + kh) * KW_;
                #pragma unroll
                for (int og = 0; og < OG; ++og) {
                    #pragma unroll
                    for (int kw = 0; kw < KW_; ++kw) {
                        float wv = wr[og * F_ + f + kw];   // uniform -> s_load
                        #pragma unroll
                        for (int p = 0; p < 4; ++p)
                            m[og][p] = fmaxf(m[og][p], fabsf(xv[p + kw] - wv));
                    }
                }
            }
        }
        __syncthreads();   // before next phase overwrites LDS
    }

    // ---- epilogue: add bias, coalesced float4 store ----
    #pragma unroll
    for (int og = 0; og < OG; ++og) {
        float b = bias[o0 + og];
        float4 r = make_float4(m[og][0] + b, m[og][1] + b,
                               m[og][2] + b, m[og][3] + b);
        float* dst = out + ((size_t)(n * O_ + o0 + og) * (H_ * W_)) + h * W_ + w0;
        *reinterpret_cast<float4*>(dst) = r;
    }
}

extern "C" void kernel_launch(void* const* d_in, const int* in_sizes, int n_in,
                              void* d_out, int out_size, void* d_ws, size_t ws_size,
                              hipStream_t stream) {
    const float* x  = (const float*)d_in[0];
    const float* w  = (const float*)d_in[1];
    const float* b  = (const float*)d_in[2];
    float* out      = (float*)d_out;

    dim3 grid(O_ / OG, N_);
    dim3 block(256);
    hipLaunchKernelGGL(normdist_kernel, grid, block,
                       LDS_FLOATS * sizeof(float), stream, x, w, b, out);
}

// Round 2
// 10.902 us; speedup vs baseline: 1.2087x; 1.2087x over previous
//
#include <hip/hip_runtime.h>

// NormDistConv: out[n,o,h,w] = max_f |patch(n,:,h,w)[f] - weight[o,f]| + bias[o]
// x: (8,16,32,32) f32, weight: (64,144) f32, bias: (64,) f32, out: (8,64,32,32) f32
//
// Grid: 512 blocks = (32 og-pairs, 2 h-halves, 8 n), 256 threads.
// Thread: 2 output channels x 2 horizontal pixels.
// LDS: [18 rows][16 ch][36] floats = 41.5 KB, single stage phase, 1 barrier.
// Inner loop: channel-paired max3 folding (6 subs + 3 v_max3 per 6 elems).

#define N_   8
#define C_   16
#define H_   32
#define W_   32
#define O_   64
#define KH_  3
#define KW_  3
#define F_   (C_ * KH_ * KW_)     // 144
#define PADW 36                   // row stride in floats (data at cols 1..32)
#define ROWS 18                   // 16 output rows + 2 halo
#define LDSF (ROWS * C_ * PADW)   // 10368 floats = 41472 B

__global__ __launch_bounds__(256)
void normdist_kernel(const float* __restrict__ x,
                     const float* __restrict__ weight,
                     const float* __restrict__ bias,
                     float* __restrict__ out)
{
    __shared__ float xs[LDSF];    // [r][c][w]
    const int tid = threadIdx.x;
    const int o0  = blockIdx.x * 2;
    const int h0  = blockIdx.y * 16;
    const int n   = blockIdx.z;

    const float* __restrict__ xn = x + (size_t)n * (C_ * H_ * W_);
    const float* __restrict__ wr = weight + (size_t)o0 * F_;   // block-uniform

    // ---- zero the two border columns (0 and 33) ----
    for (int t = tid; t < ROWS * C_; t += 256) {
        xs[t * PADW + 0]  = 0.f;
        xs[t * PADW + 33] = 0.f;
    }

    // ---- stage 18 rows x 16 ch x 32 w (9 float4 per thread, coalesced) ----
    #pragma unroll
    for (int k = 0; k < 9; ++k) {
        int idx = tid + k * 256;          // 0..2303
        int wq  = idx & 7;                // float4 index within row
        int c   = (idx >> 3) & 15;
        int r   = idx >> 7;               // 0..17
        int grow = h0 - 1 + r;            // global row incl. halo
        float4 v = make_float4(0.f, 0.f, 0.f, 0.f);
        if (grow >= 0 && grow < H_)
            v = *reinterpret_cast<const float4*>(xn + c * (H_ * W_) + grow * W_ + wq * 4);
        float* dst = &xs[(r * C_ + c) * PADW + 1 + wq * 4];
        dst[0] = v.x; dst[1] = v.y; dst[2] = v.z; dst[3] = v.w;
    }
    __syncthreads();

    // thread -> (local row, w-pair)
    const int hl = tid >> 4;              // 0..15
    const int w0 = (tid & 15) << 1;       // 0,2,...,30

    float m[2][2];                        // [og][p], statically indexed
    m[0][0] = m[0][1] = m[1][0] = m[1][1] = 0.f;

    #pragma unroll
    for (int cp = 0; cp < 8; ++cp) {      // channel pairs
        #pragma unroll
        for (int kh = 0; kh < KH_; ++kh) {
            const int rbase = (hl + kh) * C_;
            const float* rowA = &xs[(rbase + 2 * cp    ) * PADW + w0];
            const float* rowB = &xs[(rbase + 2 * cp + 1) * PADW + w0];
            float2 a01 = *reinterpret_cast<const float2*>(rowA);
            float2 a23 = *reinterpret_cast<const float2*>(rowA + 2);
            float2 b01 = *reinterpret_cast<const float2*>(rowB);
            float2 b23 = *reinterpret_cast<const float2*>(rowB + 2);
            float xa[4] = {a01.x, a01.y, a23.x, a23.y};
            float xb[4] = {b01.x, b01.y, b23.x, b23.y};
            const int fA = ((2 * cp    ) * KH_ + kh) * KW_;
            const int fB = ((2 * cp + 1) * KH_ + kh) * KW_;
            #pragma unroll
            for (int og = 0; og < 2; ++og) {
                const float wA0 = wr[og * F_ + fA + 0];
                const float wA1 = wr[og * F_ + fA + 1];
                const float wA2 = wr[og * F_ + fA + 2];
                const float wB0 = wr[og * F_ + fB + 0];
                const float wB1 = wr[og * F_ + fB + 1];
                const float wB2 = wr[og * F_ + fB + 2];
                #pragma unroll
                for (int p = 0; p < 2; ++p) {
                    float v0 = __builtin_fabsf(xa[p + 0] - wA0);
                    float v1 = __builtin_fabsf(xa[p + 1] - wA1);
                    float v2 = __builtin_fabsf(xa[p + 2] - wA2);
                    float v3 = __builtin_fabsf(xb[p + 0] - wB0);
                    float v4 = __builtin_fabsf(xb[p + 1] - wB1);
                    float v5 = __builtin_fabsf(xb[p + 2] - wB2);
                    // nested fmaxf -> v_max3_f32 (abs folds into input modifier)
                    float mm = m[og][p];
                    mm = fmaxf(fmaxf(mm, v0), v1);
                    mm = fmaxf(fmaxf(mm, v2), v3);
                    mm = fmaxf(fmaxf(mm, v4), v5);
                    m[og][p] = mm;
                }
            }
        }
    }

    // ---- epilogue: bias + float2 stores ----
    const float b0 = bias[o0 + 0];
    const float b1 = bias[o0 + 1];
    float* dst0 = out + ((size_t)(n * O_ + o0) * (H_ * W_)) + (h0 + hl) * W_ + w0;
    *reinterpret_cast<float2*>(dst0) = make_float2(m[0][0] + b0, m[0][1] + b0);
    float* dst1 = dst0 + H_ * W_;
    *reinterpret_cast<float2*>(dst1) = make_float2(m[1][0] + b1, m[1][1] + b1);
}

extern "C" void kernel_launch(void* const* d_in, const int* in_sizes, int n_in,
                              void* d_out, int out_size, void* d_ws, size_t ws_size,
                              hipStream_t stream) {
    const float* x  = (const float*)d_in[0];
    const float* w  = (const float*)d_in[1];
    const float* b  = (const float*)d_in[2];
    float* out      = (float*)d_out;

    dim3 grid(O_ / 2, 2, N_);   // 32 og-pairs x 2 h-halves x 8 n = 512 blocks
    dim3 block(256);
    hipLaunchKernelGGL(normdist_kernel, grid, block, 0, stream, x, w, b, out);
}